// Round 6
// baseline (331.711 us; speedup 1.0000x reference)
//
#include <hip/hip_runtime.h>
#include <hip/hip_bf16.h>
#include <cfloat>
#include <math.h>

#define NFULL 4096
#define NPOOL 1024
#define NTOK  5120
#define VDIM  4096

typedef __attribute__((ext_vector_type(8))) short short8;   // 8 bf16 (4 VGPR)
typedef __attribute__((ext_vector_type(4))) float f4;       // MFMA acc
typedef unsigned long long u64;

#define MFMA16(a,b,c) __builtin_amdgcn_mfma_f32_16x16x32_bf16((a),(b),(c),0,0,0)

// ======================= prep: transposes + casts ==========================
__global__ void prep_k(const float* __restrict__ z, const float* __restrict__ cbk,
                       const float* __restrict__ Wq, const float* __restrict__ Wv,
                       float* __restrict__ X, __hip_bfloat16* __restrict__ Xh,
                       __hip_bfloat16* __restrict__ cbh,
                       __hip_bfloat16* __restrict__ WqT, __hip_bfloat16* __restrict__ WvT) {
    __shared__ float smem[33 * 32];
    int bx = blockIdx.x;
    if (bx < 2048) {                       // ---- build_x (32 t x 32 c x 4 b)
        float (*tile)[33] = (float(*)[33])smem;
        int t0 = (bx & 31) * 32, c0 = ((bx >> 5) & 15) * 32, b = bx >> 9;
        int tx = threadIdx.x & 31, ty = threadIdx.x >> 5;
        #pragma unroll
        for (int i = 0; i < 4; ++i) {
            int c = ty + i * 8;
            tile[c][tx] = z[((b << 9) + c0 + c) * 1024 + t0 + tx];
        }
        __syncthreads();
        #pragma unroll
        for (int i = 0; i < 4; ++i) {
            int tl = ty + i * 8;
            int tok = (b << 10) + t0 + tl;
            Xh[tok * 512 + c0 + tx] = __float2bfloat16(tile[tx][tl]);
        }
        float m = 0.25f * (tile[tx][ty * 4] + tile[tx][ty * 4 + 1] +
                           tile[tx][ty * 4 + 2] + tile[tx][ty * 4 + 3]);
        int tq = (t0 >> 2) + ty;
        X[(NFULL + (b << 8) + tq) * 512 + c0 + tx] = m;
    } else if (bx < 4096) {                // ---- codebook cast
        int i0 = (bx - 2048) * 1024 + threadIdx.x * 4;
        float4 v = *(const float4*)(cbk + i0);
        __hip_bfloat16* d = cbh + i0;
        d[0] = __float2bfloat16(v.x); d[1] = __float2bfloat16(v.y);
        d[2] = __float2bfloat16(v.z); d[3] = __float2bfloat16(v.w);
    } else {                               // ---- W transpose+cast
        int lin = bx - 4096;
        const float* W = (lin >> 8) ? Wv : Wq;
        __hip_bfloat16* WT = (lin >> 8) ? WvT : WqT;
        float (*t)[33] = (float(*)[33])smem;
        int bk = ((lin >> 4) & 15) * 32, bn = (lin & 15) * 32;
        int lx = threadIdx.x & 31, ly = threadIdx.x >> 5;
        #pragma unroll
        for (int i = 0; i < 4; ++i) {
            int r = ly * 4 + i;
            t[r][lx] = W[(bk + r) * 512 + bn + lx];
        }
        __syncthreads();
        #pragma unroll
        for (int i = 0; i < 4; ++i) {
            int r = ly * 4 + i;
            WT[(bn + r) * 512 + bk + lx] = __float2bfloat16(t[lx][r]);
        }
    }
}

// ======================= pool-c: wave per token ============================
__global__ void pool_c2_k(const __hip_bfloat16* __restrict__ Xh,
                          const float* __restrict__ Xp,
                          const float* __restrict__ Wp, const float* __restrict__ bp,
                          float* __restrict__ Cp) {
    __shared__ float Wl[4160];             // lane stride 65 -> 2 lanes/bank
    for (int i = threadIdx.x; i < 4096; i += 256) Wl[i + (i >> 6)] = Wp[i];
    __syncthreads();
    int w = threadIdx.x >> 6, lane = threadIdx.x & 63;
    int tok = blockIdx.x * 4 + w;          // 0..5119
    float x[8];
    if (tok < NFULL) {
        short8 xv = *(const short8*)(Xh + tok * 512 + lane * 8);
        #pragma unroll
        for (int j = 0; j < 8; ++j)
            x[j] = __uint_as_float(((unsigned)(unsigned short)xv[j]) << 16);
    } else {
        const float* xp = Xp + (tok - NFULL) * 512 + lane * 8;
        float4 a = *(const float4*)xp, b = *(const float4*)(xp + 4);
        x[0] = a.x; x[1] = a.y; x[2] = a.z; x[3] = a.w;
        x[4] = b.x; x[5] = b.y; x[6] = b.z; x[7] = b.w;
    }
    float s[8] = {};
    int base = lane * 65;
    #pragma unroll
    for (int j = 0; j < 8; ++j)
        #pragma unroll
        for (int h = 0; h < 8; ++h)
            s[h] = fmaf(x[j], Wl[base + j * 8 + h], s[h]);
    #pragma unroll
    for (int h = 0; h < 8; ++h)
        #pragma unroll
        for (int o = 32; o > 0; o >>= 1) s[h] += __shfl_xor(s[h], o);
    if (lane == 0) {
        #pragma unroll
        for (int h = 0; h < 8; ++h) Cp[tok * 8 + h] = s[h] + bp[h];
    }
}

// ======================= fp32 projection GEMM ==============================
__global__ __launch_bounds__(256) void proj_split_k(
    const float* __restrict__ cbk, const float* __restrict__ Xp,
    const float* __restrict__ Wk, const float* __restrict__ Wq,
    float* __restrict__ P0, float* __restrict__ P1) {
    __shared__ float As[16][68];
    __shared__ float Bs[16][132];
    int tid = threadIdx.x;
    int mB = blockIdx.x * 64, nB = blockIdx.y * 128, kOff = blockIdx.z * 256;
    const float *A, *B;
    if (mB < NFULL) { A = cbk + mB * 512; B = Wk; }
    else            { A = Xp + (mB - NFULL) * 512; B = Wq; }
    int ty = tid >> 4, tx = tid & 15;
    int arow = tid >> 2, achk = tid & 3;
    int brow = tid >> 4, bcol = (tid & 15) * 4;
    const float* Ap = A + arow * 512 + kOff + achk * 4;
    const float* Bp = B + (kOff + brow) * 512 + nB + bcol;
    float acc[4][8] = {};
    for (int kt = 0; kt < 16; ++kt) {
        float4 a  = *(const float4*)(Ap + kt * 16);
        float4 b0 = *(const float4*)(Bp + kt * 16 * 512);
        float4 b1 = *(const float4*)(Bp + kt * 16 * 512 + 64);
        __syncthreads();
        As[achk * 4 + 0][arow] = a.x; As[achk * 4 + 1][arow] = a.y;
        As[achk * 4 + 2][arow] = a.z; As[achk * 4 + 3][arow] = a.w;
        *(float4*)&Bs[brow][bcol]      = b0;
        *(float4*)&Bs[brow][bcol + 64] = b1;
        __syncthreads();
        #pragma unroll
        for (int kk = 0; kk < 16; ++kk) {
            float4 av  = *(const float4*)&As[kk][ty * 4];
            float4 bv0 = *(const float4*)&Bs[kk][tx * 4];
            float4 bv1 = *(const float4*)&Bs[kk][64 + tx * 4];
            float a4[4] = {av.x, av.y, av.z, av.w};
            float b8[8] = {bv0.x, bv0.y, bv0.z, bv0.w, bv1.x, bv1.y, bv1.z, bv1.w};
            #pragma unroll
            for (int i = 0; i < 4; ++i)
                #pragma unroll
                for (int j = 0; j < 8; ++j)
                    acc[i][j] = fmaf(a4[i], b8[j], acc[i][j]);
        }
    }
    float* P = blockIdx.z ? P1 : P0;
    #pragma unroll
    for (int i = 0; i < 4; ++i) {
        int row = mB + ty * 4 + i;
        float4 r0, r1;
        r0.x = acc[i][0]; r0.y = acc[i][1]; r0.z = acc[i][2]; r0.w = acc[i][3];
        r1.x = acc[i][4]; r1.y = acc[i][5]; r1.z = acc[i][6]; r1.w = acc[i][7];
        *(float4*)&P[row * 512 + nB + tx * 4]      = r0;
        *(float4*)&P[row * 512 + nB + 64 + tx * 4] = r1;
    }
}

// ======================= split-K reduce + rmsnorm ==========================
__global__ void norm_finish_k(const float* __restrict__ P0, const float* __restrict__ P1,
                              const float* __restrict__ bk, const float* __restrict__ bq,
                              const float* __restrict__ gk, const float* __restrict__ gq,
                              const float* __restrict__ Cp,
                              float* __restrict__ Kn, __hip_bfloat16* __restrict__ Kh,
                              float* __restrict__ Qpool, __hip_bfloat16* __restrict__ Qh,
                              unsigned int* __restrict__ Kmax2i) {
    int row = blockIdx.x;              // 0..5119
    int t = threadIdx.x;               // cols t and t+256
    bool isQ = row >= NFULL;
    const float* bias = isQ ? bq : bk;
    const float* g = isQ ? gq : gk;
    float v0 = P0[row * 512 + t] + P1[row * 512 + t] + bias[t];
    float v1 = P0[row * 512 + t + 256] + P1[row * 512 + t + 256] + bias[t + 256];
    float s0 = v0 * v0, s1 = v1 * v1;
    #pragma unroll
    for (int o = 32; o > 0; o >>= 1) { s0 += __shfl_xor(s0, o); s1 += __shfl_xor(s1, o); }
    float gd = g[t & 63];
    float o0 = v0 * rsqrtf(s0 * (1.0f / 64.0f) + 1e-5f) * gd;
    float o1 = v1 * rsqrtf(s1 * (1.0f / 64.0f) + 1e-5f) * gd;
    if (isQ) {
        float c0f = Cp[row * 8 + (t >> 6)] * 0.04419417382415922f;   // 1/(8*sqrt8)
        float c1f = Cp[row * 8 + 4 + (t >> 6)] * 0.04419417382415922f;
        o0 *= c0f; o1 *= c1f;
        Qpool[(row - NFULL) * 512 + t] = o0;
        Qpool[(row - NFULL) * 512 + t + 256] = o1;
        Qh[row * 512 + t] = __float2bfloat16(o0);
        Qh[row * 512 + t + 256] = __float2bfloat16(o1);
    } else {
        Kn[row * 512 + t] = o0;       Kn[row * 512 + t + 256] = o1;
        Kh[row * 512 + t] = __float2bfloat16(o0);
        Kh[row * 512 + t + 256] = __float2bfloat16(o1);
        float rs = o0 * o0 + o1 * o1;
        #pragma unroll
        for (int o = 32; o > 0; o >>= 1) rs += __shfl_xor(rs, o);
        __shared__ float wsum[4];
        if ((t & 63) == 0) wsum[t >> 6] = rs;
        __syncthreads();
        if (t == 0) {
            float tot = wsum[0] + wsum[1] + wsum[2] + wsum[3];
            atomicMax(Kmax2i, __float_as_uint(tot));
        }
    }
}

// ======================= bf16 MFMA 128x128, REGISTER-DIRECT, no LDS ========
// Each wave owns a 64x64 tile; A/B fragments are loaded straight from global
// in MFMA layout (lane quad*16+lm reads row lm, 16B chunk quad — 64B
// contiguous segments per row, L2-resident: A rows reused 32x, B rows 40x
// across blocks). No LDS => no barriers => per-wave register double-buffer
// pipelines loads behind MFMAs with compiler-emitted fine-grained vmcnt.
#define RGEMM_PROLOG(AM, Bt)                                                   \
    int tid = threadIdx.x;                                                     \
    int mB = blockIdx.x * 128, nB = blockIdx.y * 128;                          \
    int lane = tid & 63, w = tid >> 6, wy = w >> 1, wx = w & 1;                \
    int lm = lane & 15, quad = lane >> 4;                                      \
    const __hip_bfloat16* Apt[4]; const __hip_bfloat16* Bpt[4];                \
    _Pragma("unroll") for (int t = 0; t < 4; ++t) {                            \
        Apt[t] = (AM) + (mB + wy * 64 + t * 16 + lm) * 512 + quad * 8;         \
        Bpt[t] = (Bt) + (nB + wx * 64 + t * 16 + lm) * 512 + quad * 8;         \
    }                                                                          \
    f4 acc[4][4];                                                              \
    _Pragma("unroll") for (int i = 0; i < 4; ++i)                              \
        _Pragma("unroll") for (int j = 0; j < 4; ++j)                          \
            acc[i][j] = f4{0.f, 0.f, 0.f, 0.f};                                \
    short8 aS[2][4], bS[2][4];                                                 \
    _Pragma("unroll") for (int t = 0; t < 4; ++t) {                            \
        aS[0][t] = *(const short8*)(Apt[t]);                                   \
        bS[0][t] = *(const short8*)(Bpt[t]);                                   \
    }                                                                          \
    _Pragma("unroll") for (int kt = 0; kt < 16; ++kt) {                        \
        int cur = kt & 1, nxt = cur ^ 1;                                       \
        if (kt < 15) {                                                         \
            _Pragma("unroll") for (int t = 0; t < 4; ++t) {                    \
                aS[nxt][t] = *(const short8*)(Apt[t] + (kt + 1) * 32);         \
                bS[nxt][t] = *(const short8*)(Bpt[t] + (kt + 1) * 32);         \
            }                                                                  \
        }                                                                      \
        _Pragma("unroll") for (int mt = 0; mt < 4; ++mt)                       \
            _Pragma("unroll") for (int nt = 0; nt < 4; ++nt)                   \
                acc[mt][nt] = MFMA16(aS[cur][mt], bS[cur][nt], acc[mt][nt]);   \
    }

// fused: z=0 -> full-res Q proj + rmsnorm + c-fold -> Qh bf16
//        z=1 -> V projection -> Vb fp32
__global__ __launch_bounds__(256) void bgemm_fused_k(
    const __hip_bfloat16* __restrict__ Xh, const __hip_bfloat16* __restrict__ WqT,
    const __hip_bfloat16* __restrict__ cbh, const __hip_bfloat16* __restrict__ WvT,
    const float* __restrict__ bq, const float* __restrict__ gq,
    const float* __restrict__ cp, const float* __restrict__ bvv,
    __hip_bfloat16* __restrict__ Qh, float* __restrict__ Vb) {
    const __hip_bfloat16* AM = blockIdx.z ? cbh : Xh;
    const __hip_bfloat16* Bt = blockIdx.z ? WvT : WqT;
    RGEMM_PROLOG(AM, Bt)
    if (blockIdx.z == 0) {
        int h = blockIdx.y * 2 + wx;
        float bb[4], gg[4];
        #pragma unroll
        for (int nt = 0; nt < 4; ++nt) {
            bb[nt] = bq[h * 64 + nt * 16 + lm];
            gg[nt] = gq[nt * 16 + lm];
        }
        #pragma unroll
        for (int mt = 0; mt < 4; ++mt)
            #pragma unroll
            for (int reg = 0; reg < 4; ++reg) {
                int tok = mB + wy * 64 + mt * 16 + quad * 4 + reg;
                float vv[4], ss = 0.f;
                #pragma unroll
                for (int nt = 0; nt < 4; ++nt) {
                    vv[nt] = acc[mt][nt][reg] + bb[nt];
                    ss = fmaf(vv[nt], vv[nt], ss);
                }
                #pragma unroll
                for (int off = 1; off < 16; off <<= 1) ss += __shfl_xor(ss, off);
                float sc = rsqrtf(ss * (1.0f / 64.0f) + 1e-5f) *
                           cp[tok * 8 + h] * 0.04419417382415922f;
                #pragma unroll
                for (int nt = 0; nt < 4; ++nt)
                    Qh[tok * 512 + h * 64 + nt * 16 + lm] =
                        __float2bfloat16(vv[nt] * sc * gg[nt]);
            }
    } else {
        float bb[4];
        #pragma unroll
        for (int nt = 0; nt < 4; ++nt) bb[nt] = bvv[nB + wx * 64 + nt * 16 + lm];
        #pragma unroll
        for (int mt = 0; mt < 4; ++mt)
            #pragma unroll
            for (int reg = 0; reg < 4; ++reg) {
                int m = mB + wy * 64 + mt * 16 + quad * 4 + reg;
                #pragma unroll
                for (int nt = 0; nt < 4; ++nt)
                    Vb[m * 512 + nB + wx * 64 + nt * 16 + lm] = acc[mt][nt][reg] + bb[nt];
            }
    }
}

// logits over all 5120 tokens: full rows -> packed atomic argmax;
// pooled rows -> bf16 logit rows for candidate rescore.
__global__ __launch_bounds__(256) void logits_full_k(
    const __hip_bfloat16* __restrict__ Qh, const __hip_bfloat16* __restrict__ Kh,
    u64* __restrict__ packed, __hip_bfloat16* __restrict__ Lp) {
    RGEMM_PROLOG(Qh, Kh)
    if (blockIdx.x < 32) {
        #pragma unroll
        for (int mt = 0; mt < 4; ++mt)
            #pragma unroll
            for (int reg = 0; reg < 4; ++reg) {
                float bv = -FLT_MAX; int bi = 0;
                #pragma unroll
                for (int nt = 0; nt < 4; ++nt) {
                    float v = acc[mt][nt][reg];
                    int n = nB + wx * 64 + nt * 16 + lm;
                    if (v > bv) { bv = v; bi = n; }
                }
                #pragma unroll
                for (int off = 1; off < 16; off <<= 1) {
                    float ov = __shfl_xor(bv, off);
                    int oi = __shfl_xor(bi, off);
                    if (ov > bv || (ov == bv && oi < bi)) { bv = ov; bi = oi; }
                }
                if (lm == 0) {
                    unsigned ub = __float_as_uint(bv);
                    ub = (ub & 0x80000000u) ? ~ub : (ub | 0x80000000u);
                    u64 key = ((u64)ub << 32) | (u64)(0xFFFFFFFFu - (unsigned)bi);
                    int tok = mB + wy * 64 + mt * 16 + quad * 4 + reg;
                    atomicMax(&packed[tok], key);
                }
            }
    } else {
        #pragma unroll
        for (int mt = 0; mt < 4; ++mt)
            #pragma unroll
            for (int reg = 0; reg < 4; ++reg) {
                int tok = mB + wy * 64 + mt * 16 + quad * 4 + reg;
                long long base = (long long)(tok - NFULL) * 4096;
                #pragma unroll
                for (int nt = 0; nt < 4; ++nt)
                    Lp[base + nB + wx * 64 + nt * 16 + lm] =
                        __float2bfloat16(acc[mt][nt][reg]);
            }
    }
}

// ======================= exact rescore of pooled tokens ====================
// candidate = bf16 logit >= bf16max - delta, delta = 2^-7 * ||q|| * max||k||
// (rigorous bound: bf16 input round + store round; MFMA products exact,
// fp32 accum). Exact fp32 dot per candidate, ascending n, strict > =>
// np.argmax first-index semantics. Provably identical to fp32 argmax.
__global__ void rescore_k(const float* __restrict__ Qpool, const float* __restrict__ Kn,
                          const __hip_bfloat16* __restrict__ Lp,
                          const unsigned int* __restrict__ Kmax2i,
                          int* __restrict__ codeP) {
    int wid = threadIdx.x >> 6, lane = threadIdx.x & 63;
    int tok = blockIdx.x * 4 + wid;
    const float* q = Qpool + tok * 512;
    float4 q0 = *(const float4*)(q + lane * 8);
    float4 q1 = *(const float4*)(q + lane * 8 + 4);
    float qs = q0.x * q0.x + q0.y * q0.y + q0.z * q0.z + q0.w * q0.w +
               q1.x * q1.x + q1.y * q1.y + q1.z * q1.z + q1.w * q1.w;
    #pragma unroll
    for (int o = 32; o > 0; o >>= 1) qs += __shfl_xor(qs, o);
    float delta = 0.0078125f * sqrtf(qs) * sqrtf(__uint_as_float(*Kmax2i));
    const __hip_bfloat16* row = Lp + (long long)tok * 4096;
    float mx = -FLT_MAX;
    for (int c = 0; c < 64; ++c)
        mx = fmaxf(mx, __bfloat162float(row[c * 64 + lane]));
    #pragma unroll
    for (int o = 32; o > 0; o >>= 1) mx = fmaxf(mx, __shfl_xor(mx, o));
    float thr = mx - delta;
    float bv = -FLT_MAX; int bi = 0;
    for (int c = 0; c < 64; ++c) {
        float v = __bfloat162float(row[c * 64 + lane]);
        u64 mask = __ballot(v >= thr);
        while (mask) {
            int l = __ffsll((long long)mask) - 1;
            mask &= mask - 1;
            int n = c * 64 + l;
            const float* k = Kn + n * 512;
            float4 k0 = *(const float4*)(k + lane * 8);
            float4 k1 = *(const float4*)(k + lane * 8 + 4);
            float d = q0.x * k0.x;
            d = fmaf(q0.y, k0.y, d); d = fmaf(q0.z, k0.z, d); d = fmaf(q0.w, k0.w, d);
            d = fmaf(q1.x, k1.x, d); d = fmaf(q1.y, k1.y, d);
            d = fmaf(q1.z, k1.z, d); d = fmaf(q1.w, k1.w, d);
            #pragma unroll
            for (int o = 32; o > 0; o >>= 1) d += __shfl_xor(d, o);
            if (d > bv) { bv = d; bi = n; }   // ascending n => first-max wins
        }
    }
    if (lane == 0) codeP[tok] = bi;
}

// ======================= histogram + perplexity (one block) ================
__global__ __launch_bounds__(1024) void hist_ppl_k(const u64* __restrict__ packed,
                                                   float* __restrict__ out) {
    __shared__ int cnt[4096];
    __shared__ float red[16];
    int tid = threadIdx.x;
    for (int i = tid; i < 4096; i += 1024) cnt[i] = 0;
    __syncthreads();
    for (int i = tid; i < 4096; i += 1024) {
        int bi = (int)(0xFFFFFFFFu - (unsigned)(packed[i] & 0xFFFFFFFFu));
        atomicAdd(&cnt[bi], 1);
    }
    __syncthreads();
    float s = 0.f;
    for (int i = tid; i < 4096; i += 1024) {
        float p = (float)cnt[i] * (1.0f / 4096.0f);
        s += p * logf(p + 1e-7f);
    }
    #pragma unroll
    for (int o = 32; o > 0; o >>= 1) s += __shfl_xor(s, o);
    if ((tid & 63) == 0) red[tid >> 6] = s;
    __syncthreads();
    if (tid == 0) {
        float t = 0.f;
        #pragma unroll
        for (int i = 0; i < 16; ++i) t += red[i];
        out[0] = expf(-t);
    }
}

// ======================= z_hat gather + linear interp x4 ===================
__global__ void zhat_k(const float* __restrict__ Vv, const int* __restrict__ codeP,
                       float* __restrict__ out) {
    int idx = blockIdx.x * 256 + threadIdx.x;
    int t = idx & 1023;
    int bc = idx >> 10;
    int b = bc >> 9, c = bc & 511;
    float pos = (t + 0.5f) * 0.25f - 0.5f;
    pos = fminf(fmaxf(pos, 0.0f), 255.0f);
    float fi = floorf(pos);
    int i0 = (int)fi;
    int i1 = min(i0 + 1, 255);
    float wgt = pos - fi;
    const int* cp = codeP + (b << 8);
    float v0 = Vv[cp[i0] * 512 + c];
    float v1 = Vv[cp[i1] * 512 + c];
    out[idx] = v0 * (1.0f - wgt) + v1 * wgt;
}

extern "C" void kernel_launch(void* const* d_in, const int* in_sizes, int n_in,
                              void* d_out, int out_size, void* d_ws, size_t ws_size,
                              hipStream_t stream) {
    const float* z   = (const float*)d_in[0];
    const float* cbk = (const float*)d_in[2];
    const float* Wq  = (const float*)d_in[3];
    const float* bq  = (const float*)d_in[4];
    const float* Wk  = (const float*)d_in[5];
    const float* bk  = (const float*)d_in[6];
    const float* Wv  = (const float*)d_in[7];
    const float* bv  = (const float*)d_in[8];
    const float* Wp  = (const float*)d_in[9];
    const float* bp  = (const float*)d_in[10];
    const float* gq  = (const float*)d_in[11];
    const float* gk  = (const float*)d_in[12];
    float* out = (float*)d_out;

    // ---- workspace layout ----
    float* X      = (float*)d_ws;            // 5120*512 (only pooled rows used)
    float* Qpool  = X + 5120 * 512;          // 1024*512
    float* Kn     = Qpool + 1024 * 512;      // 4096*512
    float* Vb     = Kn + 4096 * 512;         // 4096*512
    float* Cp     = Vb + 4096 * 512;         // 5120*8
    float* P0     = Cp + 5120 * 8;           // 5120*512 (aliased by Lp later)
    float* P1     = P0 + 5120 * 512;         // 5120*512
    u64*   packed = (u64*)(P1 + 5120 * 512); // 4096
    unsigned int* Kmax2i = (unsigned int*)(packed + 4096);  // 4
    int*   codeP  = (int*)(Kmax2i + 4);      // 1024
    __hip_bfloat16* Qh  = (__hip_bfloat16*)(codeP + 1024);  // 5120*512
    __hip_bfloat16* Kh  = Qh + 5120 * 512;   // 4096*512
    __hip_bfloat16* Xh  = Kh + 4096 * 512;   // 4096*512
    __hip_bfloat16* cbh = Xh + 4096 * 512;   // 4096*512
    __hip_bfloat16* WqT = cbh + 4096 * 512;  // 512*512
    __hip_bfloat16* WvT = WqT + 512 * 512;   // 512*512
    __hip_bfloat16* Lp  = (__hip_bfloat16*)P0;  // alias: 1024*4096 bf16

    hipMemsetAsync(packed, 0, 4096 * 8 + 16, stream);
    prep_k<<<4608, 256, 0, stream>>>(z, cbk, Wq, Wv, X, Xh, cbh, WqT, WvT);
    pool_c2_k<<<1280, 256, 0, stream>>>(Xh, X + 4096 * 512, Wp, bp, Cp);
    proj_split_k<<<dim3(80, 4, 2), 256, 0, stream>>>(cbk, X + 4096 * 512, Wk, Wq, P0, P1);
    norm_finish_k<<<5120, 256, 0, stream>>>(P0, P1, bk, bq, gk, gq, Cp,
                                            Kn, Kh, Qpool, Qh, Kmax2i);
    bgemm_fused_k<<<dim3(32, 4, 2), 256, 0, stream>>>(Xh, WqT, cbh, WvT,
                                                      bq, gq, Cp, bv, Qh, Vb);
    logits_full_k<<<dim3(40, 32), 256, 0, stream>>>(Qh, Kh, packed, Lp);
    rescore_k<<<256, 256, 0, stream>>>(Qpool, Kn, Lp, Kmax2i, codeP);
    hist_ppl_k<<<1, 1024, 0, stream>>>(packed, out + 4 * 512 * 1024);
    zhat_k<<<8192, 256, 0, stream>>>(Vb, codeP, out);
}

// Round 9
// 256.931 us; speedup vs baseline: 1.2911x; 1.2911x over previous
//
#include <hip/hip_runtime.h>
#include <hip/hip_bf16.h>
#include <cfloat>
#include <math.h>

#define NFULL 4096
#define NPOOL 1024
#define NTOK  5120
#define VDIM  4096

typedef __attribute__((ext_vector_type(8))) short short8;   // 8 bf16 (4 VGPR)
typedef __attribute__((ext_vector_type(4))) float f4;       // MFMA acc
typedef unsigned long long u64;

#define MFMA16(a,b,c) __builtin_amdgcn_mfma_f32_16x16x32_bf16((a),(b),(c),0,0,0)

static __device__ __forceinline__ void gl_lds16(const void* g, void* l) {
    __builtin_amdgcn_global_load_lds(
        (const __attribute__((address_space(1))) unsigned int*)g,
        (__attribute__((address_space(3))) unsigned int*)l, 16, 0, 0);
}

// ==== bf16 MFMA 128x128 core, BK=64, XOR-swizzled LDS (r4-verified) ========
// Requires As, Bs to span 128*64 bf16 (16 KB) EACH.
#define BGEMM3_CORE(AM, Bt)                                                    \
    int lane = tid & 63, w = tid >> 6, wy = w >> 1, wx = w & 1;                \
    int lm = lane & 15, quad = lane >> 4;                                      \
    int lr8 = lane >> 3;                                                       \
    int kcs = (lane & 7) ^ lr8;                                                \
    int rS = w * 32 + lr8;                                                     \
    const __hip_bfloat16* Ag = (AM) + (mB + rS) * 512 + kcs * 8;               \
    const __hip_bfloat16* Bg = (Bt) + (nB + rS) * 512 + kcs * 8;               \
    __hip_bfloat16* Al = As + (w * 32) * 64 + lane * 8;                        \
    __hip_bfloat16* Bl = Bs + (w * 32) * 64 + lane * 8;                        \
    f4 acc[4][4];                                                              \
    _Pragma("unroll") for (int i = 0; i < 4; ++i)                              \
        _Pragma("unroll") for (int j = 0; j < 4; ++j)                          \
            acc[i][j] = f4{0.f, 0.f, 0.f, 0.f};                                \
    int aswz = lm & 7;                                                         \
    for (int kt = 0; kt < 8; ++kt) {                                           \
        __syncthreads();                                                       \
        _Pragma("unroll") for (int i = 0; i < 4; ++i) {                        \
            gl_lds16(Ag + kt * 64 + i * 8 * 512, Al + i * 8 * 64);             \
            gl_lds16(Bg + kt * 64 + i * 8 * 512, Bl + i * 8 * 64);             \
        }                                                                      \
        __syncthreads();                                                       \
        _Pragma("unroll") for (int s = 0; s < 2; ++s) {                        \
            short8 aF[4], bF[4];                                               \
            int slot = ((s * 4 + quad) ^ aswz) << 3;                           \
            _Pragma("unroll") for (int mt = 0; mt < 4; ++mt)                   \
                aF[mt] = *(const short8*)(As + (wy * 64 + mt * 16 + lm) * 64 + slot); \
            _Pragma("unroll") for (int nt = 0; nt < 4; ++nt)                   \
                bF[nt] = *(const short8*)(Bs + (wx * 64 + nt * 16 + lm) * 64 + slot); \
            _Pragma("unroll") for (int mt = 0; mt < 4; ++mt)                   \
                _Pragma("unroll") for (int nt = 0; nt < 4; ++nt)               \
                    acc[mt][nt] = MFMA16(aF[mt], bF[nt], acc[mt][nt]);         \
        }                                                                      \
    }

// ======================= prep: transposes + casts + zero-init ==============
__global__ void prep_k(const float* __restrict__ z, const float* __restrict__ cbk,
                       const float* __restrict__ Wq, const float* __restrict__ Wv,
                       float* __restrict__ X, __hip_bfloat16* __restrict__ Xh,
                       __hip_bfloat16* __restrict__ cbh,
                       __hip_bfloat16* __restrict__ WqT, __hip_bfloat16* __restrict__ WvT,
                       u64* __restrict__ packed, unsigned int* __restrict__ Kmax2i) {
    __shared__ float smem[33 * 32];
    int bx = blockIdx.x;
    if (bx < 2048) {
        float (*tile)[33] = (float(*)[33])smem;
        int t0 = (bx & 31) * 32, c0 = ((bx >> 5) & 15) * 32, b = bx >> 9;
        int tx = threadIdx.x & 31, ty = threadIdx.x >> 5;
        #pragma unroll
        for (int i = 0; i < 4; ++i) {
            int c = ty + i * 8;
            tile[c][tx] = z[((b << 9) + c0 + c) * 1024 + t0 + tx];
        }
        __syncthreads();
        #pragma unroll
        for (int i = 0; i < 4; ++i) {
            int tl = ty + i * 8;
            int tok = (b << 10) + t0 + tl;
            Xh[tok * 512 + c0 + tx] = __float2bfloat16(tile[tx][tl]);
        }
        float m = 0.25f * (tile[tx][ty * 4] + tile[tx][ty * 4 + 1] +
                           tile[tx][ty * 4 + 2] + tile[tx][ty * 4 + 3]);
        int tq = (t0 >> 2) + ty;
        X[(NFULL + (b << 8) + tq) * 512 + c0 + tx] = m;
    } else if (bx < 4096) {
        int i0 = (bx - 2048) * 1024 + threadIdx.x * 4;
        float4 v = *(const float4*)(cbk + i0);
        __hip_bfloat16* d = cbh + i0;
        d[0] = __float2bfloat16(v.x); d[1] = __float2bfloat16(v.y);
        d[2] = __float2bfloat16(v.z); d[3] = __float2bfloat16(v.w);
    } else if (bx < 4608) {
        int lin = bx - 4096;
        const float* W = (lin >> 8) ? Wv : Wq;
        __hip_bfloat16* WT = (lin >> 8) ? WvT : WqT;
        float (*t)[33] = (float(*)[33])smem;
        int bk = ((lin >> 4) & 15) * 32, bn = (lin & 15) * 32;
        int lx = threadIdx.x & 31, ly = threadIdx.x >> 5;
        #pragma unroll
        for (int i = 0; i < 4; ++i) {
            int r = ly * 4 + i;
            t[r][lx] = W[(bk + r) * 512 + bn + lx];
        }
        __syncthreads();
        #pragma unroll
        for (int i = 0; i < 4; ++i) {
            int r = ly * 4 + i;
            WT[(bn + r) * 512 + bk + lx] = __float2bfloat16(t[lx][r]);
        }
    } else {
        int i = (bx - 4608) * 256 + threadIdx.x;     // 0..4095
        packed[i] = 0ull;
        if (bx == 4608 && threadIdx.x == 0) Kmax2i[0] = 0u;
    }
}

// ======================= mid1: fp32 proj | pool-c (both depend on prep) ====
__global__ __launch_bounds__(256) void mid1_k(
    const __hip_bfloat16* __restrict__ Xh,
    const float* __restrict__ cbk, const float* __restrict__ Xp,
    const float* __restrict__ Wk, const float* __restrict__ Wq,
    const float* __restrict__ Wp, const float* __restrict__ bp,
    float* __restrict__ P0, float* __restrict__ P1, float* __restrict__ Cp) {
    __shared__ __align__(16) char smraw[16640];
    int bx = blockIdx.x, tid = threadIdx.x;
    if (bx < 640) {
        // ---------------- fp32 split-K projection ---------------------------
        float (*As2)[68]  = (float(*)[68])smraw;
        float (*Bs2)[132] = (float(*)[132])(smraw + 16 * 68 * 4);
        int kz = bx >= 320;
        int rem = bx - kz * 320;
        int mB = (rem % 80) * 64, nB = (rem / 80) * 128, kOff = kz * 256;
        const float *A, *B;
        if (mB < NFULL) { A = cbk + mB * 512; B = Wk; }
        else            { A = Xp + (mB - NFULL) * 512; B = Wq; }
        int ty = tid >> 4, tx = tid & 15;
        int arow = tid >> 2, achk = tid & 3;
        int brow = tid >> 4, bcol = (tid & 15) * 4;
        const float* Ap = A + arow * 512 + kOff + achk * 4;
        const float* Bp = B + (kOff + brow) * 512 + nB + bcol;
        float acc[4][8] = {};
        for (int kt = 0; kt < 16; ++kt) {
            float4 a  = *(const float4*)(Ap + kt * 16);
            float4 b0 = *(const float4*)(Bp + kt * 16 * 512);
            float4 b1 = *(const float4*)(Bp + kt * 16 * 512 + 64);
            __syncthreads();
            As2[achk * 4 + 0][arow] = a.x; As2[achk * 4 + 1][arow] = a.y;
            As2[achk * 4 + 2][arow] = a.z; As2[achk * 4 + 3][arow] = a.w;
            *(float4*)&Bs2[brow][bcol]      = b0;
            *(float4*)&Bs2[brow][bcol + 64] = b1;
            __syncthreads();
            #pragma unroll
            for (int kk = 0; kk < 16; ++kk) {
                float4 av  = *(const float4*)&As2[kk][ty * 4];
                float4 bv0 = *(const float4*)&Bs2[kk][tx * 4];
                float4 bv1 = *(const float4*)&Bs2[kk][64 + tx * 4];
                float a4[4] = {av.x, av.y, av.z, av.w};
                float b8[8] = {bv0.x, bv0.y, bv0.z, bv0.w, bv1.x, bv1.y, bv1.z, bv1.w};
                #pragma unroll
                for (int i = 0; i < 4; ++i)
                    #pragma unroll
                    for (int j = 0; j < 8; ++j)
                        acc[i][j] = fmaf(a4[i], b8[j], acc[i][j]);
            }
        }
        float* P = kz ? P1 : P0;
        #pragma unroll
        for (int i = 0; i < 4; ++i) {
            int row = mB + ty * 4 + i;
            float4 r0, r1;
            r0.x = acc[i][0]; r0.y = acc[i][1]; r0.z = acc[i][2]; r0.w = acc[i][3];
            r1.x = acc[i][4]; r1.y = acc[i][5]; r1.z = acc[i][6]; r1.w = acc[i][7];
            *(float4*)&P[row * 512 + nB + tx * 4]      = r0;
            *(float4*)&P[row * 512 + nB + 64 + tx * 4] = r1;
        }
    } else {
        // ---------------- head-pool weights Cp ------------------------------
        float* Wl = (float*)smraw;             // 4160 floats: lane stride 65
        for (int i = tid; i < 4096; i += 256) Wl[i + (i >> 6)] = Wp[i];
        __syncthreads();
        int w = tid >> 6, lane = tid & 63;
        int tok = (bx - 640) * 4 + w;          // 0..5119
        float x[8];
        if (tok < NFULL) {
            short8 xv = *(const short8*)(Xh + tok * 512 + lane * 8);
            #pragma unroll
            for (int j = 0; j < 8; ++j)
                x[j] = __uint_as_float(((unsigned)(unsigned short)xv[j]) << 16);
        } else {
            const float* xp = Xp + (tok - NFULL) * 512 + lane * 8;
            float4 a = *(const float4*)xp, b = *(const float4*)(xp + 4);
            x[0] = a.x; x[1] = a.y; x[2] = a.z; x[3] = a.w;
            x[4] = b.x; x[5] = b.y; x[6] = b.z; x[7] = b.w;
        }
        float s[8] = {};
        int base = lane * 65;
        #pragma unroll
        for (int j = 0; j < 8; ++j)
            #pragma unroll
            for (int h = 0; h < 8; ++h)
                s[h] = fmaf(x[j], Wl[base + j * 8 + h], s[h]);
        #pragma unroll
        for (int h = 0; h < 8; ++h)
            #pragma unroll
            for (int o = 32; o > 0; o >>= 1) s[h] += __shfl_xor(s[h], o);
        if (lane == 0) {
            #pragma unroll
            for (int h = 0; h < 8; ++h) Cp[tok * 8 + h] = s[h] + bp[h];
        }
    }
}

// ======================= mid2: bf16 bgemms | split-K norm-finish ===========
// [0,256): MFMA GEMMs (Qproj+norm reads Cp - ordered after mid1; Vproj).
// [256,5376): norm_finish row = bx-256 (reads P0/P1/Cp from mid1).
// Disjoint outputs: Qh[0..4096) + Vb  vs  Qh[4096..) + Kn/Kh/Qpool.
// NOTE: smraw MUST be 32768 B — BGEMM3_CORE uses As (16 KB) + Bs (16 KB).
// (r8 bug: 16384 here put Bs out of bounds -> cross-workgroup LDS aliasing.)
__global__ __launch_bounds__(256) void mid2_k(
    const __hip_bfloat16* __restrict__ Xh, const __hip_bfloat16* __restrict__ WqT,
    const __hip_bfloat16* __restrict__ cbh, const __hip_bfloat16* __restrict__ WvT,
    const float* __restrict__ P0, const float* __restrict__ P1,
    const float* __restrict__ bk, const float* __restrict__ bq,
    const float* __restrict__ gk, const float* __restrict__ gq,
    const float* __restrict__ Cp, const float* __restrict__ bvv,
    __hip_bfloat16* __restrict__ Qh, float* __restrict__ Vb,
    float* __restrict__ Kn, __hip_bfloat16* __restrict__ Kh,
    float* __restrict__ Qpool, unsigned int* __restrict__ Kmax2i) {
    __shared__ __align__(16) char smraw[32768];
    int bx = blockIdx.x, tid = threadIdx.x;
    if (bx < 256) {
        int part = bx >> 7, rem = bx & 127;
        int mB = (rem & 31) * 128, nB = (rem >> 5) * 128;
        const __hip_bfloat16* AM = part ? cbh : Xh;
        const __hip_bfloat16* Bt = part ? WvT : WqT;
        __hip_bfloat16* As = (__hip_bfloat16*)smraw;
        __hip_bfloat16* Bs = As + 128 * 64;
        BGEMM3_CORE(AM, Bt)
        if (part == 0) {
            int h = (rem >> 5) * 2 + wx;
            float bb[4], gg[4];
            #pragma unroll
            for (int nt = 0; nt < 4; ++nt) {
                bb[nt] = bq[h * 64 + nt * 16 + lm];
                gg[nt] = gq[nt * 16 + lm];
            }
            #pragma unroll
            for (int mt = 0; mt < 4; ++mt)
                #pragma unroll
                for (int reg = 0; reg < 4; ++reg) {
                    int tok = mB + wy * 64 + mt * 16 + quad * 4 + reg;
                    float vv[4], ss = 0.f;
                    #pragma unroll
                    for (int nt = 0; nt < 4; ++nt) {
                        vv[nt] = acc[mt][nt][reg] + bb[nt];
                        ss = fmaf(vv[nt], vv[nt], ss);
                    }
                    #pragma unroll
                    for (int off = 1; off < 16; off <<= 1) ss += __shfl_xor(ss, off);
                    float sc = rsqrtf(ss * (1.0f / 64.0f) + 1e-5f) *
                               Cp[tok * 8 + h] * 0.04419417382415922f;  // 1/(8*sqrt8)
                    #pragma unroll
                    for (int nt = 0; nt < 4; ++nt)
                        Qh[tok * 512 + h * 64 + nt * 16 + lm] =
                            __float2bfloat16(vv[nt] * sc * gg[nt]);
                }
        } else {
            float bb[4];
            #pragma unroll
            for (int nt = 0; nt < 4; ++nt) bb[nt] = bvv[nB + wx * 64 + nt * 16 + lm];
            #pragma unroll
            for (int mt = 0; mt < 4; ++mt)
                #pragma unroll
                for (int reg = 0; reg < 4; ++reg) {
                    int m = mB + wy * 64 + mt * 16 + quad * 4 + reg;
                    #pragma unroll
                    for (int nt = 0; nt < 4; ++nt)
                        Vb[m * 512 + nB + wx * 64 + nt * 16 + lm] =
                            acc[mt][nt][reg] + bb[nt];
                }
        }
    } else {
        // ---------------- split-K reduce + rmsnorm --------------------------
        int row = bx - 256;            // 0..5119
        int t = tid;                   // cols t and t+256
        bool isQ = row >= NFULL;
        const float* bias = isQ ? bq : bk;
        const float* g = isQ ? gq : gk;
        float v0 = P0[row * 512 + t] + P1[row * 512 + t] + bias[t];
        float v1 = P0[row * 512 + t + 256] + P1[row * 512 + t + 256] + bias[t + 256];
        float s0 = v0 * v0, s1 = v1 * v1;
        #pragma unroll
        for (int o = 32; o > 0; o >>= 1) { s0 += __shfl_xor(s0, o); s1 += __shfl_xor(s1, o); }
        float gd = g[t & 63];
        float o0 = v0 * rsqrtf(s0 * (1.0f / 64.0f) + 1e-5f) * gd;
        float o1 = v1 * rsqrtf(s1 * (1.0f / 64.0f) + 1e-5f) * gd;
        if (isQ) {
            float c0f = Cp[row * 8 + (t >> 6)] * 0.04419417382415922f;
            float c1f = Cp[row * 8 + 4 + (t >> 6)] * 0.04419417382415922f;
            o0 *= c0f; o1 *= c1f;
            Qpool[(row - NFULL) * 512 + t] = o0;
            Qpool[(row - NFULL) * 512 + t + 256] = o1;
            Qh[row * 512 + t] = __float2bfloat16(o0);
            Qh[row * 512 + t + 256] = __float2bfloat16(o1);
        } else {
            Kn[row * 512 + t] = o0;       Kn[row * 512 + t + 256] = o1;
            Kh[row * 512 + t] = __float2bfloat16(o0);
            Kh[row * 512 + t + 256] = __float2bfloat16(o1);
            float rs = o0 * o0 + o1 * o1;
            #pragma unroll
            for (int o = 32; o > 0; o >>= 1) rs += __shfl_xor(rs, o);
            float* wsum = (float*)smraw;
            if ((t & 63) == 0) wsum[t >> 6] = rs;
            __syncthreads();
            if (t == 0) {
                float tot = wsum[0] + wsum[1] + wsum[2] + wsum[3];
                atomicMax(Kmax2i, __float_as_uint(tot));
            }
        }
    }
}

// ==== logits over all 5120 tokens: full rows -> packed atomic argmax; ======
// ==== pooled rows -> bf16 logit rows for candidate rescore.           ======
__global__ __launch_bounds__(256) void logits_full_k(
    const __hip_bfloat16* __restrict__ Qh, const __hip_bfloat16* __restrict__ Kh,
    u64* __restrict__ packed, __hip_bfloat16* __restrict__ Lp) {
    __shared__ __hip_bfloat16 AsBuf[128 * 64];
    __shared__ __hip_bfloat16 BsBuf[128 * 64];
    __hip_bfloat16* As = AsBuf; __hip_bfloat16* Bs = BsBuf;
    int tid = threadIdx.x;
    int mB = blockIdx.x * 128, nB = blockIdx.y * 128;
    BGEMM3_CORE(Qh, Kh)
    if (blockIdx.x < 32) {
        #pragma unroll
        for (int mt = 0; mt < 4; ++mt)
            #pragma unroll
            for (int reg = 0; reg < 4; ++reg) {
                float bv = -FLT_MAX; int bi = 0;
                #pragma unroll
                for (int nt = 0; nt < 4; ++nt) {
                    float v = acc[mt][nt][reg];
                    int n = nB + wx * 64 + nt * 16 + lm;
                    if (v > bv) { bv = v; bi = n; }
                }
                #pragma unroll
                for (int off = 1; off < 16; off <<= 1) {
                    float ov = __shfl_xor(bv, off);
                    int oi = __shfl_xor(bi, off);
                    if (ov > bv || (ov == bv && oi < bi)) { bv = ov; bi = oi; }
                }
                if (lm == 0) {
                    unsigned ub = __float_as_uint(bv);
                    ub = (ub & 0x80000000u) ? ~ub : (ub | 0x80000000u);
                    u64 key = ((u64)ub << 32) | (u64)(0xFFFFFFFFu - (unsigned)bi);
                    int tok = mB + wy * 64 + mt * 16 + quad * 4 + reg;
                    atomicMax(&packed[tok], key);
                }
            }
    } else {
        #pragma unroll
        for (int mt = 0; mt < 4; ++mt)
            #pragma unroll
            for (int reg = 0; reg < 4; ++reg) {
                int tok = mB + wy * 64 + mt * 16 + quad * 4 + reg;
                long long base = (long long)(tok - NFULL) * 4096;
                #pragma unroll
                for (int nt = 0; nt < 4; ++nt)
                    Lp[base + nB + wx * 64 + nt * 16 + lm] =
                        __float2bfloat16(acc[mt][nt][reg]);
            }
    }
}

// ======================= tail: rescore | hist+perplexity ===================
__global__ __launch_bounds__(256) void tail_k(
    const float* __restrict__ Qpool, const float* __restrict__ Kn,
    const __hip_bfloat16* __restrict__ Lp, const unsigned int* __restrict__ Kmax2i,
    const u64* __restrict__ packed, int* __restrict__ codeP,
    float* __restrict__ outPpl) {
    __shared__ int cnt[4096];
    __shared__ float red[4];
    int tid = threadIdx.x;
    if (blockIdx.x < 256) {
        int wid = tid >> 6, lane = tid & 63;
        int tok = blockIdx.x * 4 + wid;
        const float* q = Qpool + tok * 512;
        float4 q0 = *(const float4*)(q + lane * 8);
        float4 q1 = *(const float4*)(q + lane * 8 + 4);
        float qs = q0.x * q0.x + q0.y * q0.y + q0.z * q0.z + q0.w * q0.w +
                   q1.x * q1.x + q1.y * q1.y + q1.z * q1.z + q1.w * q1.w;
        #pragma unroll
        for (int o = 32; o > 0; o >>= 1) qs += __shfl_xor(qs, o);
        float delta = 0.0078125f * sqrtf(qs) * sqrtf(__uint_as_float(*Kmax2i));
        const __hip_bfloat16* row = Lp + (long long)tok * 4096;
        float mx = -FLT_MAX;
        for (int c = 0; c < 64; ++c)
            mx = fmaxf(mx, __bfloat162float(row[c * 64 + lane]));
        #pragma unroll
        for (int o = 32; o > 0; o >>= 1) mx = fmaxf(mx, __shfl_xor(mx, o));
        float thr = mx - delta;
        float bv = -FLT_MAX; int bi = 0;
        for (int c = 0; c < 64; ++c) {
            float v = __bfloat162float(row[c * 64 + lane]);
            u64 mask = __ballot(v >= thr);
            while (mask) {
                int l = __ffsll((long long)mask) - 1;
                mask &= mask - 1;
                int n = c * 64 + l;
                const float* k = Kn + n * 512;
                float4 k0 = *(const float4*)(k + lane * 8);
                float4 k1 = *(const float4*)(k + lane * 8 + 4);
                float d = q0.x * k0.x;
                d = fmaf(q0.y, k0.y, d); d = fmaf(q0.z, k0.z, d); d = fmaf(q0.w, k0.w, d);
                d = fmaf(q1.x, k1.x, d); d = fmaf(q1.y, k1.y, d);
                d = fmaf(q1.z, k1.z, d); d = fmaf(q1.w, k1.w, d);
                #pragma unroll
                for (int o = 32; o > 0; o >>= 1) d += __shfl_xor(d, o);
                if (d > bv) { bv = d; bi = n; }   // ascending n => first-max wins
            }
        }
        if (lane == 0) codeP[tok] = bi;
    } else {
        for (int i = tid; i < 4096; i += 256) cnt[i] = 0;
        __syncthreads();
        for (int i = tid; i < 4096; i += 256) {
            int bi = (int)(0xFFFFFFFFu - (unsigned)(packed[i] & 0xFFFFFFFFu));
            atomicAdd(&cnt[bi], 1);
        }
        __syncthreads();
        float s = 0.f;
        for (int i = tid; i < 4096; i += 256) {
            float p = (float)cnt[i] * (1.0f / 4096.0f);
            s += p * logf(p + 1e-7f);
        }
        #pragma unroll
        for (int o = 32; o > 0; o >>= 1) s += __shfl_xor(s, o);
        if ((tid & 63) == 0) red[tid >> 6] = s;
        __syncthreads();
        if (tid == 0)
            outPpl[0] = expf(-(red[0] + red[1] + red[2] + red[3]));
    }
}

// ======================= z_hat: wave per (b, j) ============================
__global__ void zhat_k(const float* __restrict__ Vv, const int* __restrict__ codeP,
                       float* __restrict__ out) {
    int w = (blockIdx.x << 2) + (threadIdx.x >> 6);   // 0..1023
    int lane = threadIdx.x & 63;
    int b = w >> 8, j = w & 255;
    const int* cb = codeP + (b << 8);
    const float* rm = Vv + cb[max(j - 1, 0)] * 512;
    const float* r0 = Vv + cb[j] * 512;
    const float* rp = Vv + cb[min(j + 1, 255)] * 512;
    #pragma unroll
    for (int i = 0; i < 8; ++i) {
        int c = i * 64 + lane;
        float vm = rm[c], v0 = r0[c], vp = rp[c];
        float4 o;
        o.x = 0.375f * vm + 0.625f * v0;
        o.y = 0.125f * vm + 0.875f * v0;
        o.z = 0.875f * v0 + 0.125f * vp;
        o.w = 0.625f * v0 + 0.375f * vp;
        *(float4*)&out[(((b << 9) + c) << 10) + (j << 2)] = o;
    }
}

extern "C" void kernel_launch(void* const* d_in, const int* in_sizes, int n_in,
                              void* d_out, int out_size, void* d_ws, size_t ws_size,
                              hipStream_t stream) {
    const float* z   = (const float*)d_in[0];
    const float* cbk = (const float*)d_in[2];
    const float* Wq  = (const float*)d_in[3];
    const float* bq  = (const float*)d_in[4];
    const float* Wk  = (const float*)d_in[5];
    const float* bk  = (const float*)d_in[6];
    const float* Wv  = (const float*)d_in[7];
    const float* bv  = (const float*)d_in[8];
    const float* Wp  = (const float*)d_in[9];
    const float* bp  = (const float*)d_in[10];
    const float* gq  = (const float*)d_in[11];
    const float* gk  = (const float*)d_in[12];
    float* out = (float*)d_out;

    // ---- workspace layout ----
    float* X      = (float*)d_ws;            // 5120*512 (only pooled rows used)
    float* Qpool  = X + 5120 * 512;          // 1024*512
    float* Kn     = Qpool + 1024 * 512;      // 4096*512
    float* Vb     = Kn + 4096 * 512;         // 4096*512
    float* Cp     = Vb + 4096 * 512;         // 5120*8
    float* P0     = Cp + 5120 * 8;           // 5120*512 (aliased by Lp later)
    float* P1     = P0 + 5120 * 512;         // 5120*512
    u64*   packed = (u64*)(P1 + 5120 * 512); // 4096
    unsigned int* Kmax2i = (unsigned int*)(packed + 4096);  // 4
    int*   codeP  = (int*)(Kmax2i + 4);      // 1024
    __hip_bfloat16* Qh  = (__hip_bfloat16*)(codeP + 1024);  // 5120*512
    __hip_bfloat16* Kh  = Qh + 5120 * 512;   // 4096*512
    __hip_bfloat16* Xh  = Kh + 4096 * 512;   // 4096*512
    __hip_bfloat16* cbh = Xh + 4096 * 512;   // 4096*512
    __hip_bfloat16* WqT = cbh + 4096 * 512;  // 512*512
    __hip_bfloat16* WvT = WqT + 512 * 512;   // 512*512
    __hip_bfloat16* Lp  = (__hip_bfloat16*)P0;  // alias: 1024*4096 bf16

    prep_k<<<4624, 256, 0, stream>>>(z, cbk, Wq, Wv, X, Xh, cbh, WqT, WvT,
                                     packed, Kmax2i);
    mid1_k<<<1920, 256, 0, stream>>>(Xh, cbk, X + 4096 * 512, Wk, Wq, Wp, bp,
                                     P0, P1, Cp);
    mid2_k<<<5376, 256, 0, stream>>>(Xh, WqT, cbh, WvT, P0, P1, bk, bq, gk, gq,
                                     Cp, bv, Qh, Vb, Kn, Kh, Qpool, Kmax2i);
    logits_full_k<<<dim3(40, 32), 256, 0, stream>>>(Qh, Kh, packed, Lp);
    tail_k<<<257, 256, 0, stream>>>(Qpool, Kn, Lp, Kmax2i, packed, codeP,
                                    out + 4 * 512 * 1024);
    zhat_k<<<256, 256, 0, stream>>>(Vb, codeP, out);
}